// Round 13
// baseline (68.196 us; speedup 1.0000x reference)
//
#include <hip/hip_runtime.h>
#include <hip/hip_bf16.h>

#define BATCH 8
#define NPT   2048
#define DIM   512
#define NTILE 16            // 2048/128 tiles per dim
#define NTRI  136           // 16*17/2 symmetric tiles per batch
#define NBLK  (NTRI * BATCH) // 1088

typedef __attribute__((ext_vector_type(4))) float f32x4;

// ---------------- workspace layout ----------------
// xn (fp8)  : 8,388,608 B at 0
#define OFF_SQ       16777216
#define OFF_MSUM     16842752
#define OFF_PARTIALS 16842784   // 1088 floats

// ---------------- kernel 1: normalize rows, emit fp8 e4m3 + per-row |x_q|^2 ----------------
__global__ __launch_bounds__(256) void normalize_kernel(const float* __restrict__ emb,
                                                        unsigned char* __restrict__ xn,
                                                        float* __restrict__ sq) {
    const int wave = threadIdx.x >> 6;
    const int lane = threadIdx.x & 63;
    const int row  = blockIdx.x * 4 + wave;

    const float4* src = (const float4*)(emb + (size_t)row * DIM);
    float4 v0 = src[lane * 2 + 0];
    float4 v1 = src[lane * 2 + 1];

    float ss = v0.x*v0.x + v0.y*v0.y + v0.z*v0.z + v0.w*v0.w
             + v1.x*v1.x + v1.y*v1.y + v1.z*v1.z + v1.w*v1.w;
#pragma unroll
    for (int o = 32; o; o >>= 1) ss += __shfl_xor(ss, o);

    const float inv = 1.0f / fmaxf(sqrtf(ss), 1e-12f);

    const float f0 = v0.x*inv, f1 = v0.y*inv, f2 = v0.z*inv, f3 = v0.w*inv;
    const float f4 = v1.x*inv, f5 = v1.y*inv, f6 = v1.z*inv, f7 = v1.w*inv;

    int lo = __builtin_amdgcn_cvt_pk_fp8_f32(f0, f1, 0, 0);
    lo     = __builtin_amdgcn_cvt_pk_fp8_f32(f2, f3, lo, 1);
    int hi = __builtin_amdgcn_cvt_pk_fp8_f32(f4, f5, 0, 0);
    hi     = __builtin_amdgcn_cvt_pk_fp8_f32(f6, f7, hi, 1);

    float s2 = 0.f;
    {
        float a;
        a = __builtin_amdgcn_cvt_f32_fp8(lo, 0); s2 += a * a;
        a = __builtin_amdgcn_cvt_f32_fp8(lo, 1); s2 += a * a;
        a = __builtin_amdgcn_cvt_f32_fp8(lo, 2); s2 += a * a;
        a = __builtin_amdgcn_cvt_f32_fp8(lo, 3); s2 += a * a;
        a = __builtin_amdgcn_cvt_f32_fp8(hi, 0); s2 += a * a;
        a = __builtin_amdgcn_cvt_f32_fp8(hi, 1); s2 += a * a;
        a = __builtin_amdgcn_cvt_f32_fp8(hi, 2); s2 += a * a;
        a = __builtin_amdgcn_cvt_f32_fp8(hi, 3); s2 += a * a;
    }

    uint2 pk; pk.x = (unsigned)lo; pk.y = (unsigned)hi;
    *(uint2*)(xn + (size_t)row * DIM + lane * 8) = pk;

#pragma unroll
    for (int o = 32; o; o >>= 1) s2 += __shfl_xor(s2, o);
    if (lane == 0) sq[row] = s2;
}

// ---------------- kernel 2: per-batch mask sums ----------------
__global__ __launch_bounds__(256) void masksum_kernel(const float* __restrict__ mask,
                                                      float* __restrict__ msum) {
    const int b = blockIdx.x;
    float s = 0.f;
    for (int i = threadIdx.x; i < NPT; i += 256) s += mask[b * NPT + i];
#pragma unroll
    for (int o = 32; o; o >>= 1) s += __shfl_xor(s, o);
    __shared__ float ws[4];
    if ((threadIdx.x & 63) == 0) ws[threadIdx.x >> 6] = s;
    __syncthreads();
    if (threadIdx.x == 0) msum[b] = ws[0] + ws[1] + ws[2] + ws[3];
}

// ---------------- kernel 3: fp8 Gram, WHOLE-PANEL LDS, zero main-loop barriers ----------------
// fp8 K=512 makes the full 128-row A and B panels fit in LDS (64+64 KB).
// Structure: stage everything (16 gload_lds/thread) -> ONE vmcnt(0)+barrier ->
// free-running {96 ds_read_b64 + 128 MFMA}/wave with no synchronization.
// Rounds 5-12 showed the phased structure spent ~90% of each phase-slot in
// VMW/barrier rendezvous; this removes all of it.
// LDS swizzle (512-B rows): 16-B chunk phys = c ^ (row&7). Store side permutes
// whole chunks (order inside preserved -> gload_lds-compatible); read side
// phys = (2kk+lh1) ^ (llo&7) recovers the TRUE k-chunk (exact k alignment).
// Bank math: per kk, bank-pair = ((2kk+lh1)^l7)*2 + lh0 mod 16 -> 16 distinct
// pairs x 4 lanes = the b64 throughput floor (512B/instr / 128B/cyc).
__global__ __launch_bounds__(512) void gram_loss_kernel(const unsigned char* __restrict__ xn,
                                                        const float* __restrict__ sq,
                                                        const float* __restrict__ coords,
                                                        const float* __restrict__ mask,
                                                        float* __restrict__ partials) {
    __shared__ __align__(16) unsigned char ldsA[128 * 512];   // 64 KB
    __shared__ __align__(16) unsigned char ldsB[128 * 512];   // 64 KB
    __shared__ float s_sqr[128], s_sqc[128], s_mr[128], s_mc[128];
    __shared__ float s_cr[128][3], s_cc[128][3];
    __shared__ float s_wsum[8];

    // XCD-chunked: 1088 = 8 * 136; batch == XCD id -> ~1 MB panel set per XCD L2
    const int bid = blockIdx.x;
    const int b   = bid & 7;
    int r = bid >> 3;
    int tm = 0;
    while (r >= NTILE - tm) { r -= NTILE - tm; tm++; }
    const int tn = tm + r;

    const int t    = threadIdx.x;
    const int wave = t >> 6, lane = t & 63;
    const int wr = wave >> 2, wc = wave & 3;      // 2 x 4 wave grid: 64-row x 32-col tiles
    const int lhi = lane >> 4, llo = lane & 15;

    const size_t rowBaseA = (size_t)(b * NPT + tm * 128);
    const size_t rowBaseB = (size_t)(b * NPT + tn * 128);

    f32x4 acc[4][2];
#pragma unroll
    for (int i = 0; i < 4; i++)
#pragma unroll
        for (int j = 0; j < 2; j++) acc[i][j] = (f32x4){0.f, 0.f, 0.f, 0.f};

    // ---- stage the full panels: threads 0-255 -> A, 256-511 -> B; 16 loads each.
    // flat = q*256 + ls; row = flat>>5; phys chunk = flat&31; src chunk = phys ^ (row&7).
    // LDS dest = flat*16 (linear); global gather stays within 2 rows/instr (coalesced).
    {
        const int ls   = t & 255;
        const int side = t >> 8;
        unsigned char* ldsbase = side ? ldsB : ldsA;
        const unsigned char* gpanel = xn + (side ? rowBaseB : rowBaseA) * DIM;
#pragma unroll
        for (int q = 0; q < 16; q++) {
            const int flat = q * 256 + ls;
            const int row  = flat >> 5;
            const int cph  = flat & 31;
            const int csrc = cph ^ (row & 7);
            __builtin_amdgcn_global_load_lds(
                (const __attribute__((address_space(1))) void*)(gpanel + (size_t)row * DIM + csrc * 16),
                (__attribute__((address_space(3))) void*)(ldsbase + flat * 16), 16, 0, 0);
        }
    }

    // ---- stage per-row/col metadata concurrently (plain ds writes)
    if (t < 128) {
        const int gi = b * NPT + tm * 128 + t;
        s_sqr[t]   = sq[gi];
        s_mr[t]    = mask[gi];
        s_cr[t][0] = coords[(size_t)gi * 3 + 0];
        s_cr[t][1] = coords[(size_t)gi * 3 + 1];
        s_cr[t][2] = coords[(size_t)gi * 3 + 2];
    } else if (t < 256) {
        const int rr = t - 128;
        const int gi = b * NPT + tn * 128 + rr;
        s_sqc[rr]   = sq[gi];
        s_mc[rr]    = mask[gi];
        s_cc[rr][0] = coords[(size_t)gi * 3 + 0];
        s_cc[rr][1] = coords[(size_t)gi * 3 + 1];
        s_cc[rr][2] = coords[(size_t)gi * 3 + 2];
    }

    asm volatile("s_waitcnt vmcnt(0)" ::: "memory");
    __syncthreads();   // the ONLY pre-compute barrier

    // ---- free-running K loop: no barriers, compiler-scheduled lgkmcnt
    const int lh1 = lhi >> 1;          // chunk half-select within 32-k window
    const int lh0 = lhi & 1;           // 8-B half within chunk
    const int l7  = llo & 7;
    const int baseA0 = (wr * 64 + llo) * 512 + lh0 * 8;   // + mi*16*512
    const int baseB0 = (wc * 32 + llo) * 512 + lh0 * 8;   // + ni*16*512

#pragma unroll
    for (int kk = 0; kk < 16; kk++) {
        const int off = ((2 * kk + lh1) ^ l7) << 4;
        long af[4], bfr[2];
#pragma unroll
        for (int mi = 0; mi < 4; mi++)
            af[mi] = *(const long*)(ldsA + baseA0 + mi * 8192 + off);
#pragma unroll
        for (int ni = 0; ni < 2; ni++)
            bfr[ni] = *(const long*)(ldsB + baseB0 + ni * 8192 + off);
#pragma unroll
        for (int mi = 0; mi < 4; mi++)
#pragma unroll
            for (int ni = 0; ni < 2; ni++)
                acc[mi][ni] = __builtin_amdgcn_mfma_f32_16x16x32_fp8_fp8(af[mi], bfr[ni],
                                                                         acc[mi][ni], 0, 0, 0);
    }

    __syncthreads();   // meta already written pre-loop; this orders nothing extra but is cheap

    // C/D layout: col = lane&15, row = (lane>>4)*4 + reg
    float lsum = 0.f;
#pragma unroll
    for (int mi = 0; mi < 4; mi++) {
#pragma unroll
        for (int j = 0; j < 4; j++) {
            const int rl  = wr * 64 + mi * 16 + lhi * 4 + j;
            const float sqr = s_sqr[rl];
            const float mr  = s_mr[rl];
            const float cx = s_cr[rl][0], cy = s_cr[rl][1], cz = s_cr[rl][2];
#pragma unroll
            for (int ni = 0; ni < 2; ni++) {
                const int cl = wc * 32 + ni * 16 + llo;
                const float g  = acc[mi][ni][j];
                float d2 = sqr + s_sqc[cl] - 2.f * g;
                d2 = fmaxf(d2, 0.f);
                const float de = sqrtf(d2);
                const float lo = fmaxf(de - 1.0f, 0.f);
                const float dx = cx - s_cc[cl][0];
                const float dy = cy - s_cc[cl][1];
                const float dz = cz - s_cc[cl][2];
                const float cd2 = dx*dx + dy*dy + dz*dz;
                const float wgt = (cd2 < 100.0f) ? mr * s_mc[cl] : 0.f;
                lsum += lo * wgt;
            }
        }
    }
    // off-diagonal tiles stand for both (tm,tn) and (tn,tm)
    if (tm != tn) lsum *= 2.0f;

#pragma unroll
    for (int o = 32; o; o >>= 1) lsum += __shfl_xor(lsum, o);
    if (lane == 0) s_wsum[wave] = lsum;
    __syncthreads();
    if (t == 0) {
        float bs = 0.f;
#pragma unroll
        for (int i = 0; i < 8; i++) bs += s_wsum[i];
        partials[bid] = bs;
    }
}

// ---------------- kernel 4: final deterministic reduce ----------------
__global__ __launch_bounds__(256) void finalize_kernel(const float* __restrict__ partials,
                                                       const float* __restrict__ msum,
                                                       float* __restrict__ out) {
    double s = 0.0;
    for (int i = threadIdx.x; i < NBLK; i += 256) s += (double)partials[i];
#pragma unroll
    for (int o = 32; o; o >>= 1) s += __shfl_xor(s, o);
    __shared__ double ws[4];
    if ((threadIdx.x & 63) == 0) ws[threadIdx.x >> 6] = s;
    __syncthreads();
    if (threadIdx.x == 0) {
        const double tot = ws[0] + ws[1] + ws[2] + ws[3];
        double valid = 0.0;
        for (int bb = 0; bb < BATCH; bb++) valid += (double)msum[bb] * (double)msum[bb];
        out[0] = (float)(tot / (valid + 1e-8));
    }
}

extern "C" void kernel_launch(void* const* d_in, const int* in_sizes, int n_in,
                              void* d_out, int out_size, void* d_ws, size_t ws_size,
                              hipStream_t stream) {
    const float* emb    = (const float*)d_in[0];
    const float* coords = (const float*)d_in[1];
    const float* mask   = (const float*)d_in[2];

    char* ws = (char*)d_ws;
    unsigned char* xn  = (unsigned char*)ws;
    float* sq          = (float*)(ws + OFF_SQ);
    float* msum        = (float*)(ws + OFF_MSUM);
    float* partials    = (float*)(ws + OFF_PARTIALS);
    float* out         = (float*)d_out;

    normalize_kernel<<<dim3(BATCH * NPT / 4), dim3(256), 0, stream>>>(emb, xn, sq);
    masksum_kernel<<<dim3(BATCH), dim3(256), 0, stream>>>(mask, msum);
    gram_loss_kernel<<<dim3(NBLK), dim3(512), 0, stream>>>(xn, sq, coords, mask, partials);
    finalize_kernel<<<dim3(1), dim3(256), 0, stream>>>(partials, msum, out);
}